// Round 14
// baseline (400.465 us; speedup 1.0000x reference)
//
#include <hip/hip_runtime.h>
#include <stdint.h>

// ---------------------------------------------------------------------------
// NIVR: coord-MLP over 512x512 grid.
//   pre_kernel (fused): posenc tables with time branch folded -> Txp, Ty;
//                       W2f -> bf16 32x32x16-frag-swizzled W2s.
//   main_kernel: R13 structure, MFMA shape switched 16x16x32 -> 32x32x16:
//     128 MFMAs/wave (2x work each) instead of 256; half the dependency
//     edges and waitcnt events; same bytes/K. Wave tile 2mt x 2nt,
//     acc = 2x2 f32x16 (64 AGPR). K-loop: 16 iters x (4 B-loads +
//     4 ds_read_b128 + 8 MFMA), depth-2 B / depth-1 A register pipelines.
//
// Rationale: rounds 2-13 falsified L2-BW, spills, conflicts, occupancy,
// prefetch depth, phase-lock, and role-split as the binding constraint
// (plateau 229-243us, MfmaUtil ~26%). Per-instruction issue/dependency
// overhead is the last untested axis; 32x32x16 halves instruction count
// and is ~15% more pipe-efficient (2382 vs 2075 TF ubench).
// ---------------------------------------------------------------------------

typedef short bf16x8 __attribute__((ext_vector_type(8)));
typedef float f32x16 __attribute__((ext_vector_type(16)));

#define PI_F 3.14159265358979323846f
#define SIDE 512
#define NPIX (SIDE * SIDE)

__device__ __forceinline__ unsigned short f2bf(float f) {
  unsigned int u = __float_as_uint(f);
  u += 0x7fffu + ((u >> 16) & 1u);
  return (unsigned short)(u >> 16);
}

// ---------------------------------------------------------------------------
// Fused precompute kernel. Grid = 1024 blocks x 512 threads:
//   blocks 0..511  : posenc tables for coord v=b, time branch folded:
//                    Txp[v][k] = tvec[k] + sum_l enc[l] W1f[l][k]
//                    Ty [v][k] =           sum_l enc[l] W1f[20+l][k]
//   blocks 512..1023: W2f -> bf16 32x32x16 frag image (k-row = b-512):
//     tile (ks16 = k>>4, ntile = n>>5); lane = (n&31) + 32*((k>>3)&1);
//     W2s[((ks16*16 + ntile)*64 + lane)*8 + (k&7)] = bf16(W2f[k][n])
//   => B-frag read for (ks16,ntile): lane l holds B[k=ks16*16+(l>>5)*8+j]
//      [n=ntile*32+(l&31)] as one contiguous 16B at +lane*16.
// ---------------------------------------------------------------------------
__global__ void pre_kernel(const float* __restrict__ W1p, const float* __restrict__ b1p,
                           const float* __restrict__ W2p, const float* __restrict__ b2p,
                           const float* __restrict__ W1f, const float* __restrict__ b1f,
                           const float* __restrict__ W2f, const int* __restrict__ idx,
                           float* __restrict__ Txp, float* __restrict__ Ty,
                           unsigned short* __restrict__ W2s) {
  const int b = blockIdx.x;
  const int t = threadIdx.x;

  if (b >= 512) {
    const int k = b - 512, n = t;
    const int ks16 = k >> 4, h = (k >> 3) & 1, j = k & 7;
    const int ntile = n >> 5, lane = (n & 31) + 32 * h;
    W2s[((ks16 * 16 + ntile) * 64 + lane) * 8 + j] = f2bf(W2f[k * 512 + n]);
    return;
  }

  __shared__ float enc[20];
  __shared__ float r_s[32];
  __shared__ float h_s[256];
  __shared__ float phi_s[128];

  if (t < 10) {
    float u = (float)b / 512.0f;
    float ang = u * ldexpf(PI_F, t);
    enc[t] = sinf(ang);
    enc[10 + t] = cosf(ang);
  }
  if (t >= 32 && t < 48) {
    const int l = t - 32;
    float tt = (float)idx[0] / 300.0f;
    float ang = tt * ldexpf(PI_F, l);
    r_s[l] = sinf(ang);
    r_s[16 + l] = cosf(ang);
  }
  __syncthreads();
  if (t < 256) {
    float a = b1p[t];
#pragma unroll
    for (int i = 0; i < 32; ++i) a += r_s[i] * W1p[i * 256 + t];
    h_s[t] = fmaxf(a, 0.f);
  }
  __syncthreads();
  if (t < 128) {
    float a = b2p[t];
    for (int i = 0; i < 256; ++i) a += h_s[i] * W2p[i * 128 + t];
    phi_s[t] = a;
  }
  __syncthreads();
  {
    float tv = b1f[t];
    for (int p = 0; p < 128; ++p) tv += phi_s[p] * W1f[(40 + p) * 512 + t];
    float ax = tv, ay = 0.f;
#pragma unroll
    for (int l = 0; l < 20; ++l) {
      ax += enc[l] * W1f[l * 512 + t];
      ay += enc[l] * W1f[(20 + l) * 512 + t];
    }
    Txp[b * 512 + t] = ax;
    Ty[b * 512 + t] = ay;
  }
}

// ---------------------------------------------------------------------------
// Main kernel. Block = 512 thr (8 waves), BM=64 (8x8 patch), BN=512, K=512.
// Wave w owns cols [w*64, w*64+64) = n-tiles {2w, 2w+1}. 16 K-iters of 32
// (2 sub-steps of 16). A image in LDS: frag (ks16, mt) at
// ((ks16*2+mt)*64 + lane)*16B, lane-contiguous. acc = 2x2 f32x16.
// ---------------------------------------------------------------------------
__global__ __launch_bounds__(512, 2) void main_kernel(
    const float* __restrict__ Txp, const float* __restrict__ Ty,
    const unsigned short* __restrict__ W2s, const float* __restrict__ b2f,
    const float* __restrict__ W3f, const float* __restrict__ b3f,
    float* __restrict__ out) {
  __shared__ __attribute__((aligned(16))) unsigned short Ab[32768];  // 64KB
  __shared__ float part[8][64][3];                                   // 6KB

  const int t = threadIdx.x;
  const int w = t >> 6;
  const int lane = t & 63;
  const int l5 = lane >> 5;        // half-lane (row-k group)
  const int lc = lane & 31;        // col within 32 / row within 32
  const int x0 = blockIdx.x * 8, y0 = blockIdx.y * 8;

  const unsigned short* bptr = W2s + lane * 8;  // + (ks16*16 + ntile)*512
  const int nt0 = w * 2;

  // ---- B pipeline: depth 2 (in ks32 units). breg[i%3][sub*2+nt]. ----
  bf16x8 breg[3][4];
#pragma unroll
  for (int d = 0; d < 2; ++d)
#pragma unroll
    for (int sub = 0; sub < 2; ++sub)
#pragma unroll
      for (int nt = 0; nt < 2; ++nt)
        breg[d][sub * 2 + nt] =
            *(const bf16x8*)(bptr + (((d * 2 + sub) * 16) + nt0 + nt) * 512);

  // ---- A fill (once): thread (p = t>>3, s = t&7) covers pixel p,
  // k = ks32*32 + s*4..+3. Image slot: ks16 = ks32*2 + (s>>2),
  // h = (s>>1)&1, lane32 = (p&31)+32*h, mt = p>>5, j0 = (s&1)*4.
  {
    const int p = t >> 3, s = t & 7;
    const int xi = x0 + (p >> 3), yi = y0 + (p & 7);
    const float* txp = Txp + xi * 512 + s * 4;
    const float* typ = Ty + yi * 512 + s * 4;
    const int mt = p >> 5;
    const int lane32 = (p & 31) + 32 * ((s >> 1) & 1);
    const int sub0 = s >> 2, j0 = (s & 1) * 4;
#pragma unroll
    for (int ks32 = 0; ks32 < 16; ++ks32) {
      float4 a = *(const float4*)(txp + ks32 * 32);
      float4 b = *(const float4*)(typ + ks32 * 32);
      uint2 pk;
      pk.x = (unsigned)f2bf(fmaxf(a.x + b.x, 0.f)) |
             ((unsigned)f2bf(fmaxf(a.y + b.y, 0.f)) << 16);
      pk.y = (unsigned)f2bf(fmaxf(a.z + b.z, 0.f)) |
             ((unsigned)f2bf(fmaxf(a.w + b.w, 0.f)) << 16);
      const int ks16 = ks32 * 2 + sub0;
      *(uint2*)&Ab[((ks16 * 2 + mt) * 64 + lane32) * 8 + j0] = pk;
    }
  }

  f32x16 acc[2][2];
#pragma unroll
  for (int i = 0; i < 2; ++i)
#pragma unroll
    for (int j = 0; j < 2; ++j) acc[i][j] = (f32x16)(0.f);

  __syncthreads();  // publishes A; the only barrier before the epilogue

  // ---- A-frag pipeline: depth 1 (ks32 units). areg[i&1][sub*2+mt]. ----
  bf16x8 areg[2][4];
#pragma unroll
  for (int sub = 0; sub < 2; ++sub)
#pragma unroll
    for (int mt = 0; mt < 2; ++mt)
      areg[0][sub * 2 + mt] =
          *(const bf16x8*)&Ab[((sub * 2 + mt) * 64 + lane) * 8];

  // ---- K-loop: 16 iters x (4 B-loads + 4 ds_reads + 8 MFMA) ----
#pragma unroll
  for (int ks32 = 0; ks32 < 16; ++ks32) {
    if (ks32 + 2 < 16) {
#pragma unroll
      for (int sub = 0; sub < 2; ++sub)
#pragma unroll
        for (int nt = 0; nt < 2; ++nt)
          breg[(ks32 + 2) % 3][sub * 2 + nt] = *(const bf16x8*)(
              bptr + ((((ks32 + 2) * 2 + sub) * 16) + nt0 + nt) * 512);
    }
    if (ks32 + 1 < 16) {
#pragma unroll
      for (int sub = 0; sub < 2; ++sub)
#pragma unroll
        for (int mt = 0; mt < 2; ++mt)
          areg[(ks32 + 1) & 1][sub * 2 + mt] = *(const bf16x8*)
              &Ab[((((ks32 + 1) * 2 + sub) * 2 + mt) * 64 + lane) * 8];
    }
#pragma unroll
    for (int sub = 0; sub < 2; ++sub)
#pragma unroll
      for (int nt = 0; nt < 2; ++nt)
#pragma unroll
        for (int mt = 0; mt < 2; ++mt)
          acc[mt][nt] = __builtin_amdgcn_mfma_f32_32x32x16_bf16(
              areg[ks32 & 1][sub * 2 + mt], breg[ks32 % 3][sub * 2 + nt],
              acc[mt][nt], 0, 0, 0);
  }

  // ---- epilogue: C layout col=lane&31, row=(r&3)+8*(r>>2)+4*(lane>>5).
  // h2 = relu(acc + b2f); rgb partial = h2 @ W3f over this wave's 64 cols.
  float bb2[2], w3v[2][3];
#pragma unroll
  for (int nt = 0; nt < 2; ++nt) {
    const int kcol = w * 64 + nt * 32 + lc;
    bb2[nt] = b2f[kcol];
    w3v[nt][0] = W3f[kcol * 3 + 0];
    w3v[nt][1] = W3f[kcol * 3 + 1];
    w3v[nt][2] = W3f[kcol * 3 + 2];
  }
#pragma unroll
  for (int mt = 0; mt < 2; ++mt) {
    float vv[16][3];
#pragma unroll
    for (int r = 0; r < 16; ++r)
#pragma unroll
      for (int cc = 0; cc < 3; ++cc) vv[r][cc] = 0.f;
#pragma unroll
    for (int nt = 0; nt < 2; ++nt) {
#pragma unroll
      for (int r = 0; r < 16; ++r) {
        float h2 = fmaxf(acc[mt][nt][r] + bb2[nt], 0.f);
        vv[r][0] += h2 * w3v[nt][0];
        vv[r][1] += h2 * w3v[nt][1];
        vv[r][2] += h2 * w3v[nt][2];
      }
    }
    // butterfly over the 32 lanes sharing this row-group (bits 0..4)
#pragma unroll
    for (int d = 1; d < 32; d <<= 1) {
#pragma unroll
      for (int r = 0; r < 16; ++r)
#pragma unroll
        for (int cc = 0; cc < 3; ++cc)
          vv[r][cc] += __shfl_xor(vv[r][cc], d, 64);
    }
    if (lc == 0) {
#pragma unroll
      for (int r = 0; r < 16; ++r) {
        const int row = (r & 3) + 8 * (r >> 2) + 4 * l5;
#pragma unroll
        for (int cc = 0; cc < 3; ++cc) part[w][mt * 32 + row][cc] = vv[r][cc];
      }
    }
  }
  __syncthreads();
  if (t < 192) {
    const int c = t >> 6, mm = t & 63;
    float sum = b3f[c];
#pragma unroll
    for (int ww = 0; ww < 8; ++ww) sum += part[ww][mm][c];
    const int n = (x0 + (mm >> 3)) * 512 + (y0 + (mm & 7));
    out[c * NPIX + n] = sum;
  }
}

// ---------------------------------------------------------------------------
// Inputs: 0 coords (unused), 1 W1p, 2 b1p, 3 W2p, 4 b2p, 5 W1f, 6 b1f,
//         7 W2f, 8 b2f, 9 W3f, 10 b3f, 11 idx
// ---------------------------------------------------------------------------
extern "C" void kernel_launch(void* const* d_in, const int* in_sizes, int n_in,
                              void* d_out, int out_size, void* d_ws, size_t ws_size,
                              hipStream_t stream) {
  const float* W1p = (const float*)d_in[1];
  const float* b1p = (const float*)d_in[2];
  const float* W2p = (const float*)d_in[3];
  const float* b2p = (const float*)d_in[4];
  const float* W1f = (const float*)d_in[5];
  const float* b1f = (const float*)d_in[6];
  const float* W2f = (const float*)d_in[7];
  const float* b2f = (const float*)d_in[8];
  const float* W3f = (const float*)d_in[9];
  const float* b3f = (const float*)d_in[10];
  const int* idx = (const int*)d_in[11];
  float* out = (float*)d_out;

  char* ws = (char*)d_ws;
  float* Txp = (float*)ws;                                   // 1 MB
  float* Ty = (float*)(ws + (1u << 20));                     // 1 MB
  unsigned short* W2s = (unsigned short*)(ws + (2u << 20));  // 512 KB

  hipLaunchKernelGGL(pre_kernel, dim3(1024), dim3(512), 0, stream,
                     W1p, b1p, W2p, b2p, W1f, b1f, W2f, idx, Txp, Ty, W2s);
  hipLaunchKernelGGL(main_kernel, dim3(64, 64), dim3(512), 0, stream,
                     Txp, Ty, W2s, b2f, W3f, b3f, out);
}